// Round 5
// baseline (309.752 us; speedup 1.0000x reference)
//
#include <hip/hip_runtime.h>

// ---------------------------------------------------------------------------
// ConvCaps (EM routing): b=8, B=32, C=32, K=3, stride=2, Win=13, Wout=6, 3 iters
// x: (8, 544, 13, 13) f32   [pose 512ch = (q,r,o), act 32ch]
// W: (3,3,32,32,4,4) f32    [ch=(ij*32+o)][c][p][q], 512 floats per ch
// out: (8, 544, 6, 6) f32
// vote[d=p*4+r] = sum_q W[ch][c][p][q] * pose[n,q,r,o, 2x+i, 2y+j]
//
// Fused M+E kernel: grid = 8 c_grps x 96 spatial-chunks(3) = 768 blocks
// (3 blocks/CU -> 3 waves/SIMD; R4's 1 wave/SIMD was the latency exposure).
// Wave = one c; W slice (5 k-slots x 16) lives in VGPRs across 3 spatials.
// votesE == votes (kperm only permutes the output slot) -> votes cached in
// VGPRs from M, E is just (v-mu)^2 + exp. p_hat slices are block-private;
// only D (all-c child normalizer) crosses blocks -> ping-pong D0/D1.
// ---------------------------------------------------------------------------

// workspace layout (floats)
#define OFF_PHAT 0           // 288*32*288 = 2654208   [spatial][c][slot]
#define OFF_D0   2654208     // 43264  [n][pix][o]
#define OFF_D1   2697472     // 43264
#define OFF_POST 2740736     // 692224 = 8*32*169*16
#define OFF_ACTT 3432960     // 43264  [n][pix][o]
// total 3476224 floats = 13.9 MB

__device__ __forceinline__ float wred64(float v) {
#pragma unroll
  for (int m = 32; m >= 1; m >>= 1) v += __shfl_xor(v, m, 64);
  return v;
}

__device__ __forceinline__ void load16(const float* __restrict__ p, float* dst) {
  const float4* p4 = (const float4*)p;
  float4 a = p4[0], b = p4[1], c = p4[2], d = p4[3];
  dst[0]=a.x; dst[1]=a.y; dst[2]=a.z; dst[3]=a.w;
  dst[4]=b.x; dst[5]=b.y; dst[6]=b.z; dst[7]=b.w;
  dst[8]=c.x; dst[9]=c.y; dst[10]=c.z; dst[11]=c.w;
  dst[12]=d.x; dst[13]=d.y; dst[14]=d.z; dst[15]=d.w;
}

// pose transpose: x[n,(q*4+r)*32+o,pix] -> posT[((n*32+o)*169+pix)*16 + d]
__global__ __launch_bounds__(256) void prep_pose(const float* __restrict__ x,
                                                 float* __restrict__ posT) {
  int tid = blockIdx.x * 256 + threadIdx.x;   // 692224 = 2704*256
  int pix = tid % 169; int t = tid / 169;
  int o = t & 31; t >>= 5;
  int d = t & 15; int n = t >> 4;
  float v = x[((size_t)n * 544 + d * 32 + o) * 169 + pix];
  posT[((size_t)(n * 32 + o) * 169 + pix) * 16 + d] = v;
}

// act transpose: x[n, 512+o, pix] -> actT[(n*169+pix)*32 + o]
__global__ __launch_bounds__(256) void prep_act(const float* __restrict__ x,
                                                float* __restrict__ actT) {
  int tid = blockIdx.x * 256 + threadIdx.x;   // 43264 = 169*256
  int pix = tid % 169; int t = tid / 169;
  int o = t & 31; int n = t >> 5;
  float v = x[(size_t)n * 91936 + 86528 + o * 169 + pix];
  actT[((size_t)n * 169 + pix) * 32 + o] = v;
}

// Fused EM step.
// mode 0: M(uniform Rp) + E -> p_hat, Dwrite
// mode 1: M(p_hat, Dread) + E -> p_hat, Dwrite
// mode 2: M(p_hat, Dread) -> final output
__global__ __launch_bounds__(256, 3) void em_kernel(
    const float* __restrict__ Wt, const float* __restrict__ posT,
    const float* __restrict__ actT, float* __restrict__ p_hat,
    const float* __restrict__ Dread, float* __restrict__ Dwrite,
    const float* __restrict__ beta_v, const float* __restrict__ beta_a,
    const float* __restrict__ lambda_, float* __restrict__ out, int mode) {
  __shared__ float sP[288 * 20];   // pose patch, stride 20 (2-way ~free)
  __shared__ float sE[288];        // a/1152 or a/D per child slot
  __shared__ float sPh[4 * 288];   // per-wave p_hat by slot, for D reduce

  const int g = blockIdx.x & 7;        // c group
  const int u = blockIdx.x >> 3;       // spatial chunk (3 spatials), 0..95
  const int wave = threadIdx.x >> 6;
  const int lane = threadIdx.x & 63;
  const int c = g * 4 + wave;

  // ---- one-time W preload: lane's 5 child-slots x 16 floats ----
  float Wreg[5][16];
#pragma unroll
  for (int k = 0; k < 5; ++k) {
    int ch = lane + 64 * k; if (ch > 287) ch = 287;
    load16(Wt + (size_t)ch * 512 + c * 16, Wreg[k]);
  }
  const float bvv = beta_v[0], bav = beta_a[0], lamv = lambda_[0];

  for (int sidx = 0; sidx < 3; ++sidx) {
    const int sg = u * 3 + sidx;
    int t = sg;
    const int y = t % 6; t /= 6;
    const int xx = t % 6;
    const int n = t / 6;

    __syncthreads();   // prev spatial's sP/sE/sPh fully consumed

    // ---- prefetch p_hat (global, coalesced) so vmcnt overlaps staging ----
    float phv[5];
    if (mode != 0) {
      const float* phb = p_hat + ((size_t)sg * 32 + c) * 288;
#pragma unroll
      for (int k = 0; k < 5; ++k) {
        int ch = lane + 64 * k; if (ch > 287) ch = 287;
        phv[k] = phb[ch];
      }
    }

    // ---- stage pose patch (coalesced float4) ----
    for (int task = threadIdx.x; task < 1152; task += 256) {
      int ch = task >> 2, q = task & 3;
      int o = ch & 31, ij = ch >> 5;
      int i = ij / 3, j = ij - i * 3;
      int pix = (2 * xx + i) * 13 + (2 * y + j);
      float4 v = *(const float4*)(posT +
          ((size_t)((n * 32 + o) * 169) + pix) * 16 + q * 4);
      *(float4*)(sP + ch * 20 + q * 4) = v;
    }
    // ---- stage rhat scale: a/1152 or a/D (32-contiguous reads) ----
    for (int task = threadIdx.x; task < 288; task += 256) {
      int o = task & 31, ij = task >> 5;
      int i = ij / 3, j = ij - i * 3;
      int idx = ((size_t)n * 169 + (2 * xx + i) * 13 + (2 * y + j)) * 32 + o;
      float a = actT[idx];
      sE[task] = (mode == 0) ? a * (1.0f / 1152.0f) : a / Dread[idx];
    }
    __syncthreads();

    // ---- M step ----
    float votes[5][16];
    float sum_r = 0.f, sv[16], sq[16];
#pragma unroll
    for (int d = 0; d < 16; ++d) { sv[d] = 0.f; sq[d] = 0.f; }

#pragma unroll
    for (int k = 0; k < 5; ++k) {
      int ch = lane + 64 * k;
      const bool act_l = (ch < 288);
      const int chm = act_l ? ch : 0;
      float P[16];
      load16(sP + chm * 20, P);
      float rhat = sE[chm];
      if (mode != 0) rhat *= phv[k];
      if (!act_l) rhat = 0.f;
      sum_r += rhat;
#pragma unroll
      for (int p = 0; p < 4; ++p)
#pragma unroll
        for (int r = 0; r < 4; ++r) {
          float v = Wreg[k][p * 4 + 0] * P[0 + r] + Wreg[k][p * 4 + 1] * P[4 + r] +
                    Wreg[k][p * 4 + 2] * P[8 + r] + Wreg[k][p * 4 + 3] * P[12 + r];
          votes[k][p * 4 + r] = v;
          sv[p * 4 + r] = fmaf(rhat, v, sv[p * 4 + r]);
          sq[p * 4 + r] = fmaf(rhat * v, v, sq[p * 4 + r]);
        }
    }

    sum_r = wred64(sum_r);
    const float inv_sr = 1.0f / sum_r;
    float mu[16];
    float lsum = 0.f;
#pragma unroll
    for (int d = 0; d < 16; ++d) {
      float s1 = wred64(sv[d]);
      float s2 = wred64(sq[d]);
      float m = s1 * inv_sr;
      mu[d] = m;
      float sg_ = fmaxf(s2 * inv_sr - m * m, 1e-30f);
      lsum += __logf(sg_);
    }
    const float cost = (16.f * bvv + lsum) * sum_r;
    const float aout = 1.0f / (1.0f + __expf(-lamv * (bav - cost)));

    if (mode == 2) {
      if (lane == 0) {
        float* ob = out + (size_t)(n * 544 + c * 16) * 36 + xx * 6 + y;
#pragma unroll
        for (int d = 0; d < 16; ++d) ob[d * 36] = mu[d];
        out[(size_t)(n * 544 + 512 + c) * 36 + xx * 6 + y] = aout;
      }
      continue;   // uniform across block
    }

    // ---- E step (votesE values == votes; only output slot is permuted) ----
    const float G = __logf(aout) - 0.5f * (lsum + 16.f * 1.8378770664093453f);
#pragma unroll
    for (int k = 0; k < 5; ++k) {
      int mch = lane + 64 * k;
      if (mch < 288) {
        float ss = 0.f;
#pragma unroll
        for (int d = 0; d < 16; ++d) {
          float dv = votes[k][d] - mu[d];
          ss = fmaf(dv, dv, ss);
        }
        float ph = __expf(G - ss);
        int o = mch & 31, ijm = mch >> 5;
        int im = ijm / 3, jm = ijm - im * 3;
        int i2 = (im == 0) ? 0 : 3 - im;   // kperm = {0,2,1}, involution
        int j2 = (jm == 0) ? 0 : 3 - jm;
        int slot = (i2 * 3 + j2) * 32 + o;
        p_hat[((size_t)sg * 32 + c) * 288 + slot] = ph;
        sPh[wave * 288 + slot] = ph;
      }
    }
    __syncthreads();
    // D reduce over block's 4 c + global atomic (8 c-grp blocks contribute)
    for (int t2 = threadIdx.x; t2 < 288; t2 += 256) {
      float s = sPh[t2] + sPh[288 + t2] + sPh[576 + t2] + sPh[864 + t2];
      int o = t2 & 31, ij = t2 >> 5;
      int i = ij / 3, j = ij - i * 3;
      atomicAdd(Dwrite + ((size_t)n * 169 + (2 * xx + i) * 13 + (2 * y + j)) * 32 + o, s);
    }
  }
}

extern "C" void kernel_launch(void* const* d_in, const int* in_sizes, int n_in,
                              void* d_out, int out_size, void* d_ws,
                              size_t ws_size, hipStream_t stream) {
  const float* x   = (const float*)d_in[0];
  const float* Wt  = (const float*)d_in[1];
  const float* bv  = (const float*)d_in[2];
  const float* ba  = (const float*)d_in[3];
  const float* lam = (const float*)d_in[4];
  float* out = (float*)d_out;
  float* ws = (float*)d_ws;

  float* p_hat = ws + OFF_PHAT;
  float* D0    = ws + OFF_D0;
  float* D1    = ws + OFF_D1;
  float* posT  = ws + OFF_POST;
  float* actT  = ws + OFF_ACTT;

  (void)in_sizes; (void)n_in; (void)out_size; (void)ws_size;

  prep_pose<<<2704, 256, 0, stream>>>(x, posT);
  prep_act<<<169, 256, 0, stream>>>(x, actT);
  hipMemsetAsync(D0, 0, 43264 * sizeof(float), stream);
  hipMemsetAsync(D1, 0, 43264 * sizeof(float), stream);

  // M0 + E1 -> p_hat, D0
  em_kernel<<<768, 256, 0, stream>>>(Wt, posT, actT, p_hat, D1, D0,
                                     bv, ba, lam, out, 0);
  // M1 (p_hat, D0) + E2 -> p_hat, D1
  em_kernel<<<768, 256, 0, stream>>>(Wt, posT, actT, p_hat, D0, D1,
                                     bv, ba, lam, out, 1);
  // M2 (p_hat, D1) -> out
  em_kernel<<<768, 256, 0, stream>>>(Wt, posT, actT, p_hat, D1, D0,
                                     bv, ba, lam, out, 2);
}

// Round 6
// 241.489 us; speedup vs baseline: 1.2827x; 1.2827x over previous
//
#include <hip/hip_runtime.h>

// ---------------------------------------------------------------------------
// ConvCaps (EM routing): b=8, B=32, C=32, K=3, stride=2, Win=13, Wout=6, 3 iters
// x: (8, 544, 13, 13) f32   [pose 512ch = (q,r,o), act 32ch]
// W: (3,3,32,32,4,4) f32    [ch=(ij*32+o)][c][p][q], 512 floats per ch
// out: (8, 544, 6, 6) f32
// vote[d=p*4+r] = sum_q W[ch][c][p][q] * pose[n,q,r,o, 2x+i, 2y+j]
//
// Fused M+E kernel: grid = 8 c_grps x 96 spatial-chunks(3) = 768 blocks
// (3 blocks/CU = 3 waves/SIMD). Wave = one c.
// Register budget (the R5 lesson): Wreg[5][16]=80 + votes[5][16]=80 + acc 32
// spilled 225 MB of scratch at (256,3). Fix: NO votes cache — E recomputes
// votes from sP+Wreg (~1.3k cyc) instead of 80 VGPRs. Peak live ~160 regs.
// W transposed to [c][ch][16] so the preload is lane-contiguous (coalesced).
// p_hat slices are block-private; only D crosses blocks -> ping-pong D0/D1.
// ---------------------------------------------------------------------------

// workspace layout (floats)
#define OFF_PHAT 0           // 288*32*288 = 2654208   [spatial][c][slot]
#define OFF_D0   2654208     // 43264  [n][pix][o]
#define OFF_D1   2697472     // 43264
#define OFF_POST 2740736     // 692224 = 8*32*169*16
#define OFF_ACTT 3432960     // 43264  [n][pix][o]
#define OFF_WT2  3476224     // 147456 = 32*288*16  [c][ch][d]
// total 3623680 floats = 14.5 MB

__device__ __forceinline__ float wred64(float v) {
#pragma unroll
  for (int m = 32; m >= 1; m >>= 1) v += __shfl_xor(v, m, 64);
  return v;
}

__device__ __forceinline__ void load16(const float* __restrict__ p, float* dst) {
  const float4* p4 = (const float4*)p;
  float4 a = p4[0], b = p4[1], c = p4[2], d = p4[3];
  dst[0]=a.x; dst[1]=a.y; dst[2]=a.z; dst[3]=a.w;
  dst[4]=b.x; dst[5]=b.y; dst[6]=b.z; dst[7]=b.w;
  dst[8]=c.x; dst[9]=c.y; dst[10]=c.z; dst[11]=c.w;
  dst[12]=d.x; dst[13]=d.y; dst[14]=d.z; dst[15]=d.w;
}

// pose transpose: x[n,(q*4+r)*32+o,pix] -> posT[((n*32+o)*169+pix)*16 + d]
__global__ __launch_bounds__(256) void prep_pose(const float* __restrict__ x,
                                                 float* __restrict__ posT) {
  int tid = blockIdx.x * 256 + threadIdx.x;   // 692224 = 2704*256
  int pix = tid % 169; int t = tid / 169;
  int o = t & 31; t >>= 5;
  int d = t & 15; int n = t >> 4;
  float v = x[((size_t)n * 544 + d * 32 + o) * 169 + pix];
  posT[((size_t)(n * 32 + o) * 169 + pix) * 16 + d] = v;
}

// act transpose: x[n, 512+o, pix] -> actT[(n*169+pix)*32 + o]
__global__ __launch_bounds__(256) void prep_act(const float* __restrict__ x,
                                                float* __restrict__ actT) {
  int tid = blockIdx.x * 256 + threadIdx.x;   // 43264 = 169*256
  int pix = tid % 169; int t = tid / 169;
  int o = t & 31; int n = t >> 5;
  float v = x[(size_t)n * 91936 + 86528 + o * 169 + pix];
  actT[((size_t)n * 169 + pix) * 32 + o] = v;
}

// W transpose: Wt[ch][c][d] -> Wt2[c][ch][d]  (coalesced wave preload)
__global__ __launch_bounds__(256) void prep_w(const float* __restrict__ Wt,
                                              float* __restrict__ Wt2) {
  int tid = blockIdx.x * 256 + threadIdx.x;   // 147456 = 576*256
  int c = tid / 4608; int r = tid - c * 4608;
  int ch = r >> 4, d = r & 15;
  Wt2[tid] = Wt[(size_t)ch * 512 + c * 16 + d];
}

// Fused EM step.
// mode 0: M(uniform Rp) + E -> p_hat, Dwrite
// mode 1: M(p_hat, Dread) + E -> p_hat, Dwrite
// mode 2: M(p_hat, Dread) -> final output
__global__ __launch_bounds__(256, 3) void em_kernel(
    const float* __restrict__ Wt2, const float* __restrict__ posT,
    const float* __restrict__ actT, float* __restrict__ p_hat,
    const float* __restrict__ Dread, float* __restrict__ Dwrite,
    const float* __restrict__ beta_v, const float* __restrict__ beta_a,
    const float* __restrict__ lambda_, float* __restrict__ out, int mode) {
  __shared__ float sP[288 * 20];   // pose patch, stride 20 (2-way ~free)
  __shared__ float sE[288];        // a/1152 or a/D per child slot
  __shared__ float sPh[4 * 288];   // per-wave p_hat by slot, for D reduce

  const int g = blockIdx.x & 7;        // c group
  const int u = blockIdx.x >> 3;       // spatial chunk (3 spatials), 0..95
  const int wave = threadIdx.x >> 6;
  const int lane = threadIdx.x & 63;
  const int c = g * 4 + wave;

  // ---- one-time W preload: lane-contiguous, coalesced ----
  float Wreg[5][16];
  {
    const float* wbase = Wt2 + (size_t)c * 4608;
#pragma unroll
    for (int k = 0; k < 5; ++k) {
      int ch = lane + 64 * k; if (ch > 287) ch = 287;
      load16(wbase + ch * 16, Wreg[k]);
    }
  }
  const float bvv = beta_v[0], bav = beta_a[0], lamv = lambda_[0];

  for (int sidx = 0; sidx < 3; ++sidx) {
    const int sg = u * 3 + sidx;
    int t = sg;
    const int y = t % 6; t /= 6;
    const int xx = t % 6;
    const int n = t / 6;

    __syncthreads();   // prev spatial's sP/sE/sPh fully consumed

    // ---- prefetch p_hat (global, coalesced) so vmcnt overlaps staging ----
    float phv[5];
    if (mode != 0) {
      const float* phb = p_hat + ((size_t)sg * 32 + c) * 288;
#pragma unroll
      for (int k = 0; k < 5; ++k) {
        int ch = lane + 64 * k; if (ch > 287) ch = 287;
        phv[k] = phb[ch];
      }
    }

    // ---- stage pose patch (coalesced float4) ----
    for (int task = threadIdx.x; task < 1152; task += 256) {
      int ch = task >> 2, q = task & 3;
      int o = ch & 31, ij = ch >> 5;
      int i = ij / 3, j = ij - i * 3;
      int pix = (2 * xx + i) * 13 + (2 * y + j);
      float4 v = *(const float4*)(posT +
          ((size_t)((n * 32 + o) * 169) + pix) * 16 + q * 4);
      *(float4*)(sP + ch * 20 + q * 4) = v;
    }
    // ---- stage rhat scale: a/1152 or a/D (32-contiguous reads) ----
    for (int task = threadIdx.x; task < 288; task += 256) {
      int o = task & 31, ij = task >> 5;
      int i = ij / 3, j = ij - i * 3;
      int idx = ((size_t)n * 169 + (2 * xx + i) * 13 + (2 * y + j)) * 32 + o;
      float a = actT[idx];
      sE[task] = (mode == 0) ? a * (1.0f / 1152.0f) : a / Dread[idx];
    }
    __syncthreads();

    // ---- M step ----
    float sum_r = 0.f, sv[16], sq[16];
#pragma unroll
    for (int d = 0; d < 16; ++d) { sv[d] = 0.f; sq[d] = 0.f; }

#pragma unroll
    for (int k = 0; k < 5; ++k) {
      int ch = lane + 64 * k;
      const bool act_l = (ch < 288);
      const int chm = act_l ? ch : 0;
      float P[16];
      load16(sP + chm * 20, P);
      float rhat = sE[chm];
      if (mode != 0) rhat *= phv[k];
      if (!act_l) rhat = 0.f;
      sum_r += rhat;
#pragma unroll
      for (int p = 0; p < 4; ++p)
#pragma unroll
        for (int r = 0; r < 4; ++r) {
          float v = Wreg[k][p * 4 + 0] * P[0 + r] + Wreg[k][p * 4 + 1] * P[4 + r] +
                    Wreg[k][p * 4 + 2] * P[8 + r] + Wreg[k][p * 4 + 3] * P[12 + r];
          sv[p * 4 + r] = fmaf(rhat, v, sv[p * 4 + r]);
          sq[p * 4 + r] = fmaf(rhat * v, v, sq[p * 4 + r]);
        }
    }

    sum_r = wred64(sum_r);
    const float inv_sr = 1.0f / sum_r;
    float mu[16];
    float lsum = 0.f;
#pragma unroll
    for (int d = 0; d < 16; ++d) {
      float s1 = wred64(sv[d]);
      float s2 = wred64(sq[d]);
      float m = s1 * inv_sr;
      mu[d] = m;
      float sg_ = fmaxf(s2 * inv_sr - m * m, 1e-30f);
      lsum += __logf(sg_);
    }
    const float cost = (16.f * bvv + lsum) * sum_r;
    const float aout = 1.0f / (1.0f + __expf(-lamv * (bav - cost)));

    if (mode == 2) {
      if (lane == 0) {
        float* ob = out + (size_t)(n * 544 + c * 16) * 36 + xx * 6 + y;
#pragma unroll
        for (int d = 0; d < 16; ++d) ob[d * 36] = mu[d];
        out[(size_t)(n * 544 + 512 + c) * 36 + xx * 6 + y] = aout;
      }
      continue;   // uniform across block
    }

    // ---- E step: recompute votes from sP + Wreg (saves 80 VGPRs vs cache) ----
    const float G = __logf(aout) - 0.5f * (lsum + 16.f * 1.8378770664093453f);
#pragma unroll
    for (int k = 0; k < 5; ++k) {
      int mch = lane + 64 * k;
      if (mch < 288) {
        float P[16];
        load16(sP + mch * 20, P);
        float ss = 0.f;
#pragma unroll
        for (int p = 0; p < 4; ++p)
#pragma unroll
          for (int r = 0; r < 4; ++r) {
            float v = Wreg[k][p * 4 + 0] * P[0 + r] + Wreg[k][p * 4 + 1] * P[4 + r] +
                      Wreg[k][p * 4 + 2] * P[8 + r] + Wreg[k][p * 4 + 3] * P[12 + r];
            float dv = v - mu[p * 4 + r];
            ss = fmaf(dv, dv, ss);
          }
        float ph = __expf(G - ss);
        int o = mch & 31, ijm = mch >> 5;
        int im = ijm / 3, jm = ijm - im * 3;
        int i2 = (im == 0) ? 0 : 3 - im;   // kperm = {0,2,1}, involution
        int j2 = (jm == 0) ? 0 : 3 - jm;
        int slot = (i2 * 3 + j2) * 32 + o;
        p_hat[((size_t)sg * 32 + c) * 288 + slot] = ph;
        sPh[wave * 288 + slot] = ph;
      }
    }
    __syncthreads();
    // D reduce over block's 4 c + global atomic (8 c-grp blocks contribute)
    for (int t2 = threadIdx.x; t2 < 288; t2 += 256) {
      float s = sPh[t2] + sPh[288 + t2] + sPh[576 + t2] + sPh[864 + t2];
      int o = t2 & 31, ij = t2 >> 5;
      int i = ij / 3, j = ij - i * 3;
      atomicAdd(Dwrite + ((size_t)n * 169 + (2 * xx + i) * 13 + (2 * y + j)) * 32 + o, s);
    }
  }
}

extern "C" void kernel_launch(void* const* d_in, const int* in_sizes, int n_in,
                              void* d_out, int out_size, void* d_ws,
                              size_t ws_size, hipStream_t stream) {
  const float* x   = (const float*)d_in[0];
  const float* Wt  = (const float*)d_in[1];
  const float* bv  = (const float*)d_in[2];
  const float* ba  = (const float*)d_in[3];
  const float* lam = (const float*)d_in[4];
  float* out = (float*)d_out;
  float* ws = (float*)d_ws;

  float* p_hat = ws + OFF_PHAT;
  float* D0    = ws + OFF_D0;
  float* D1    = ws + OFF_D1;
  float* posT  = ws + OFF_POST;
  float* actT  = ws + OFF_ACTT;
  float* Wt2   = ws + OFF_WT2;

  (void)in_sizes; (void)n_in; (void)out_size; (void)ws_size;

  prep_pose<<<2704, 256, 0, stream>>>(x, posT);
  prep_act<<<169, 256, 0, stream>>>(x, actT);
  prep_w<<<576, 256, 0, stream>>>(Wt, Wt2);
  hipMemsetAsync(D0, 0, 43264 * sizeof(float), stream);
  hipMemsetAsync(D1, 0, 43264 * sizeof(float), stream);

  // M0 + E1 -> p_hat, D0
  em_kernel<<<768, 256, 0, stream>>>(Wt2, posT, actT, p_hat, D1, D0,
                                     bv, ba, lam, out, 0);
  // M1 (p_hat, D0) + E2 -> p_hat, D1
  em_kernel<<<768, 256, 0, stream>>>(Wt2, posT, actT, p_hat, D0, D1,
                                     bv, ba, lam, out, 1);
  // M2 (p_hat, D1) -> out
  em_kernel<<<768, 256, 0, stream>>>(Wt2, posT, actT, p_hat, D1, D0,
                                     bv, ba, lam, out, 2);
}

// Round 7
// 174.282 us; speedup vs baseline: 1.7773x; 1.3856x over previous
//
#include <hip/hip_runtime.h>

// ---------------------------------------------------------------------------
// ConvCaps (EM routing): b=8, B=32, C=32, K=3, stride=2, Win=13, Wout=6, 3 iters
// x: (8, 544, 13, 13) f32   [pose 512ch = (q,r,o), act 32ch]
// W: (3,3,32,32,4,4) f32    [ch=(ij*32+o)][c][p][q], 512 floats per ch
// out: (8, 544, 6, 6) f32
// vote[d=p*4+r] = sum_q W[ch][c][p][q] * pose[n,q,r,o, 2x+i, 2y+j]
//
// Fused M+E kernel: grid = 2304 blocks = 8 c_grps x 288 spatials, chunk=1.
// Wave = one c. NO W register cache (R5/R6 lesson: 80 VGPRs of W forces the
// compiler to clamp at ~84 regs and spill 30-200 MB of scratch). W is loaded
// per-k from Wt2[c][ch][16] - lane-contiguous, coalesced, L2-resident 576 KB.
// Live set ~110 regs; __launch_bounds__(256,2) leaves headroom -> no spill.
// votesE == votes (kperm only permutes the output slot); E recomputes votes
// from sP + Wm. p_hat slices are block-private across dispatches (same
// blockIdx -> same XCD); only D crosses blocks -> ping-pong D0/D1.
// ---------------------------------------------------------------------------

// workspace layout (floats)
#define OFF_PHAT 0           // 288*32*288 = 2654208   [spatial][c][slot]
#define OFF_D0   2654208     // 43264  [n][pix][o]
#define OFF_D1   2697472     // 43264
#define OFF_POST 2740736     // 692224 = 8*32*169*16
#define OFF_ACTT 3432960     // 43264  [n][pix][o]
#define OFF_WT2  3476224     // 147456 = 32*288*16  [c][ch][d]
// total 3623680 floats = 14.5 MB

__device__ __forceinline__ float wred64(float v) {
#pragma unroll
  for (int m = 32; m >= 1; m >>= 1) v += __shfl_xor(v, m, 64);
  return v;
}

__device__ __forceinline__ void load16(const float* __restrict__ p, float* dst) {
  const float4* p4 = (const float4*)p;
  float4 a = p4[0], b = p4[1], c = p4[2], d = p4[3];
  dst[0]=a.x; dst[1]=a.y; dst[2]=a.z; dst[3]=a.w;
  dst[4]=b.x; dst[5]=b.y; dst[6]=b.z; dst[7]=b.w;
  dst[8]=c.x; dst[9]=c.y; dst[10]=c.z; dst[11]=c.w;
  dst[12]=d.x; dst[13]=d.y; dst[14]=d.z; dst[15]=d.w;
}

// One fused prep kernel (range-branched elementwise):
//   [0,692224)        pose transpose -> posT
//   [692224,735488)   act transpose  -> actT
//   [735488,882944)   W transpose    -> Wt2
//   [882944,969472)   zero D0 and D1
__global__ __launch_bounds__(256) void prep_kernel(
    const float* __restrict__ x, const float* __restrict__ Wt,
    float* __restrict__ posT, float* __restrict__ actT,
    float* __restrict__ Wt2, float* __restrict__ Dz) {
  int tid = blockIdx.x * 256 + threadIdx.x;   // 969472 = 3787*256
  if (tid < 692224) {
    int pix = tid % 169; int t = tid / 169;
    int o = t & 31; t >>= 5;
    int d = t & 15; int n = t >> 4;
    float v = x[((size_t)n * 544 + d * 32 + o) * 169 + pix];
    posT[((size_t)(n * 32 + o) * 169 + pix) * 16 + d] = v;
  } else if (tid < 735488) {
    int r = tid - 692224;
    int pix = r % 169; int t = r / 169;
    int o = t & 31; int n = t >> 5;
    float v = x[(size_t)n * 91936 + 86528 + o * 169 + pix];
    actT[((size_t)n * 169 + pix) * 32 + o] = v;
  } else if (tid < 882944) {
    int r = tid - 735488;                     // 147456 = 32*288*16
    int c = r / 4608; int s = r - c * 4608;
    int ch = s >> 4, d = s & 15;
    Wt2[r] = Wt[(size_t)ch * 512 + c * 16 + d];
  } else {
    Dz[tid - 882944] = 0.f;                   // D0 then D1 (contiguous)
  }
}

// Fused EM step.
// mode 0: M(uniform Rp) + E -> p_hat, Dwrite
// mode 1: M(p_hat, Dread) + E -> p_hat, Dwrite
// mode 2: M(p_hat, Dread) -> final output
__global__ __launch_bounds__(256, 2) void em_kernel(
    const float* __restrict__ Wt2, const float* __restrict__ posT,
    const float* __restrict__ actT, float* __restrict__ p_hat,
    const float* __restrict__ Dread, float* __restrict__ Dwrite,
    const float* __restrict__ beta_v, const float* __restrict__ beta_a,
    const float* __restrict__ lambda_, float* __restrict__ out, int mode) {
  __shared__ float sP[288 * 20];   // pose patch, stride 20 (float4-aligned)
  __shared__ float sE[288];        // a/1152 or a/D per child slot
  __shared__ float sPh[4 * 288];   // per-wave p_hat by slot, for D reduce

  const int g = blockIdx.x & 7;        // c group
  const int sg = blockIdx.x >> 3;      // spatial 0..287
  const int wave = threadIdx.x >> 6;
  const int lane = threadIdx.x & 63;
  const int c = g * 4 + wave;

  int t = sg;
  const int y = t % 6; t /= 6;
  const int xx = t % 6;
  const int n = t / 6;

  const float bvv = beta_v[0], bav = beta_a[0], lamv = lambda_[0];
  const float* wbase = Wt2 + (size_t)c * 4608;

  // ---- prefetch p_hat (global, coalesced) so vmcnt overlaps staging ----
  float phv[5];
  if (mode != 0) {
    const float* phb = p_hat + ((size_t)sg * 32 + c) * 288;
#pragma unroll
    for (int k = 0; k < 5; ++k) {
      int ch = lane + 64 * k; if (ch > 287) ch = 287;
      phv[k] = phb[ch];
    }
  }

  // ---- stage pose patch (coalesced float4) ----
  for (int task = threadIdx.x; task < 1152; task += 256) {
    int ch = task >> 2, q = task & 3;
    int o = ch & 31, ij = ch >> 5;
    int i = ij / 3, j = ij - i * 3;
    int pix = (2 * xx + i) * 13 + (2 * y + j);
    float4 v = *(const float4*)(posT +
        ((size_t)((n * 32 + o) * 169) + pix) * 16 + q * 4);
    *(float4*)(sP + ch * 20 + q * 4) = v;
  }
  // ---- stage rhat scale: a/1152 or a/D (32-contiguous reads) ----
  for (int task = threadIdx.x; task < 288; task += 256) {
    int o = task & 31, ij = task >> 5;
    int i = ij / 3, j = ij - i * 3;
    int idx = ((size_t)n * 169 + (2 * xx + i) * 13 + (2 * y + j)) * 32 + o;
    float a = actT[idx];
    sE[task] = (mode == 0) ? a * (1.0f / 1152.0f) : a / Dread[idx];
  }
  __syncthreads();

  // ---- M step (W loaded per-k from L2-warm Wt2, coalesced) ----
  float sum_r = 0.f, sv[16], sq[16];
#pragma unroll
  for (int d = 0; d < 16; ++d) { sv[d] = 0.f; sq[d] = 0.f; }

#pragma unroll
  for (int k = 0; k < 5; ++k) {
    int ch = lane + 64 * k;
    const bool act_l = (ch < 288);
    const int chm = act_l ? ch : 0;
    float P[16], Wm[16];
    load16(sP + chm * 20, P);
    load16(wbase + chm * 16, Wm);
    float rhat = sE[chm];
    if (mode != 0) rhat *= phv[k];
    if (!act_l) rhat = 0.f;
    sum_r += rhat;
#pragma unroll
    for (int p = 0; p < 4; ++p)
#pragma unroll
      for (int r = 0; r < 4; ++r) {
        float v = Wm[p * 4 + 0] * P[0 + r] + Wm[p * 4 + 1] * P[4 + r] +
                  Wm[p * 4 + 2] * P[8 + r] + Wm[p * 4 + 3] * P[12 + r];
        sv[p * 4 + r] = fmaf(rhat, v, sv[p * 4 + r]);
        sq[p * 4 + r] = fmaf(rhat * v, v, sq[p * 4 + r]);
      }
  }

  sum_r = wred64(sum_r);
  const float inv_sr = 1.0f / sum_r;
  float mu[16];
  float lsum = 0.f;
#pragma unroll
  for (int d = 0; d < 16; ++d) {
    float s1 = wred64(sv[d]);
    float s2 = wred64(sq[d]);
    float m = s1 * inv_sr;
    mu[d] = m;
    float sg_ = fmaxf(s2 * inv_sr - m * m, 1e-30f);
    lsum += __logf(sg_);
  }
  const float cost = (16.f * bvv + lsum) * sum_r;
  const float aout = 1.0f / (1.0f + __expf(-lamv * (bav - cost)));

  if (mode == 2) {
    if (lane == 0) {
      float* ob = out + (size_t)(n * 544 + c * 16) * 36 + xx * 6 + y;
#pragma unroll
      for (int d = 0; d < 16; ++d) ob[d * 36] = mu[d];
      out[(size_t)(n * 544 + 512 + c) * 36 + xx * 6 + y] = aout;
    }
    return;
  }

  // ---- E step: recompute votes from sP + Wm (no register cache) ----
  const float G = __logf(aout) - 0.5f * (lsum + 16.f * 1.8378770664093453f);
#pragma unroll
  for (int k = 0; k < 5; ++k) {
    int mch = lane + 64 * k;
    if (mch < 288) {
      float P[16], Wm[16];
      load16(sP + mch * 20, P);
      load16(wbase + mch * 16, Wm);
      float ss = 0.f;
#pragma unroll
      for (int p = 0; p < 4; ++p)
#pragma unroll
        for (int r = 0; r < 4; ++r) {
          float v = Wm[p * 4 + 0] * P[0 + r] + Wm[p * 4 + 1] * P[4 + r] +
                    Wm[p * 4 + 2] * P[8 + r] + Wm[p * 4 + 3] * P[12 + r];
          float dv = v - mu[p * 4 + r];
          ss = fmaf(dv, dv, ss);
        }
      float ph = __expf(G - ss);
      int o = mch & 31, ijm = mch >> 5;
      int im = ijm / 3, jm = ijm - im * 3;
      int i2 = (im == 0) ? 0 : 3 - im;   // kperm = {0,2,1}, involution
      int j2 = (jm == 0) ? 0 : 3 - jm;
      int slot = (i2 * 3 + j2) * 32 + o;
      p_hat[((size_t)sg * 32 + c) * 288 + slot] = ph;
      sPh[wave * 288 + slot] = ph;
    }
  }
  __syncthreads();
  // D reduce over block's 4 c + global atomic (8 c-grp blocks contribute)
  for (int t2 = threadIdx.x; t2 < 288; t2 += 256) {
    float s = sPh[t2] + sPh[288 + t2] + sPh[576 + t2] + sPh[864 + t2];
    int o = t2 & 31, ij = t2 >> 5;
    int i = ij / 3, j = ij - i * 3;
    atomicAdd(Dwrite + ((size_t)n * 169 + (2 * xx + i) * 13 + (2 * y + j)) * 32 + o, s);
  }
}

extern "C" void kernel_launch(void* const* d_in, const int* in_sizes, int n_in,
                              void* d_out, int out_size, void* d_ws,
                              size_t ws_size, hipStream_t stream) {
  const float* x   = (const float*)d_in[0];
  const float* Wt  = (const float*)d_in[1];
  const float* bv  = (const float*)d_in[2];
  const float* ba  = (const float*)d_in[3];
  const float* lam = (const float*)d_in[4];
  float* out = (float*)d_out;
  float* ws = (float*)d_ws;

  float* p_hat = ws + OFF_PHAT;
  float* D0    = ws + OFF_D0;
  float* D1    = ws + OFF_D1;
  float* posT  = ws + OFF_POST;
  float* actT  = ws + OFF_ACTT;
  float* Wt2   = ws + OFF_WT2;

  (void)in_sizes; (void)n_in; (void)out_size; (void)ws_size;

  // fused prep: transposes + zero D0/D1 (D0,D1 contiguous in ws)
  prep_kernel<<<3787, 256, 0, stream>>>(x, Wt, posT, actT, Wt2, D0);

  // M0 + E1 -> p_hat, D0
  em_kernel<<<2304, 256, 0, stream>>>(Wt2, posT, actT, p_hat, D1, D0,
                                      bv, ba, lam, out, 0);
  // M1 (p_hat, D0) + E2 -> p_hat, D1
  em_kernel<<<2304, 256, 0, stream>>>(Wt2, posT, actT, p_hat, D0, D1,
                                      bv, ba, lam, out, 1);
  // M2 (p_hat, D1) -> out
  em_kernel<<<2304, 256, 0, stream>>>(Wt2, posT, actT, p_hat, D1, D0,
                                      bv, ba, lam, out, 2);
}